// Round 3
// baseline (623.666 us; speedup 1.0000x reference)
//
#include <hip/hip_runtime.h>
#include <hip/hip_bf16.h>

// SparseMoE: N=2048, D_IN=1024, D_HID=4096, D_OUT=1024, E=8, K=2.
// R3: conflict-free LDS layout (lane->row(l&15),chunk(l>>4) staging; fragment
// reads at linear lane*16), BK=64 (half the barriers), GEMM2 split-K=4 with
// plain partial stores (no atomics, no Y memset; reduce in combine).

#define N_TOK   2048
#define D_IN    1024
#define D_HID   4096
#define D_OUT   1024
#define NEXP    8
#define TOPK    2
#define ROW_CAP 5120   // max padded rows: 4096 + 8*127 = 5112, round up

typedef __bf16 bf16x8 __attribute__((ext_vector_type(8)));
typedef float  f32x4  __attribute__((ext_vector_type(4)));

__device__ inline unsigned short f2bf(float f) {
    union { float f; unsigned u; } v; v.f = f;
    unsigned u = v.u;
    return (unsigned short)((u + 0x7FFFu + ((u >> 16) & 1u)) >> 16);  // RNE
}
__device__ inline unsigned pack2(float lo, float hi) {
    return (unsigned)f2bf(lo) | ((unsigned)f2bf(hi) << 16);
}
__device__ inline void async_copy16(const void* g, void* l) {
    __builtin_amdgcn_global_load_lds(
        (const __attribute__((address_space(1))) void*)g,
        (__attribute__((address_space(3))) void*)l, 16, 0, 0);
}

// ---------------- weight convert: fp32 -> bf16, grid-stride ----------------
__global__ __launch_bounds__(256) void convert_w(
    const float4* __restrict__ src, uint2* __restrict__ dst, int n4)
{
    int idx = blockIdx.x * 256 + threadIdx.x;
    int stride = gridDim.x * 256;
    for (int i = idx; i < n4; i += stride) {
        float4 f = src[i];
        uint2 p; p.x = pack2(f.x, f.y); p.y = pack2(f.z, f.w);
        dst[i] = p;
    }
}

// ---------------- gate: 1 wave per token ----------------
__global__ __launch_bounds__(256) void gate_kernel(
    const float* __restrict__ x, const float* __restrict__ gw,
    const float* __restrict__ gb, int* __restrict__ topi,
    float* __restrict__ topw, int* __restrict__ counts)
{
    int wave = threadIdx.x >> 6, lane = threadIdx.x & 63;
    int t = blockIdx.x * 4 + wave;
    const float* xt = x + (size_t)t * D_IN;
    float acc[NEXP];
#pragma unroll
    for (int e = 0; e < NEXP; e++) acc[e] = 0.f;
    for (int i = 0; i < D_IN / 64; i++) {
        float xv = xt[lane + 64 * i];
#pragma unroll
        for (int e = 0; e < NEXP; e++)
            acc[e] += xv * gw[e * D_IN + lane + 64 * i];
    }
#pragma unroll
    for (int e = 0; e < NEXP; e++) {
        float v = acc[e];
#pragma unroll
        for (int m = 32; m; m >>= 1) v += __shfl_xor(v, m, 64);
        acc[e] = v + gb[e];
    }
    if (lane == 0) {
        float b1v = -1e30f; int i1 = 0;
#pragma unroll
        for (int e = 0; e < NEXP; e++) if (acc[e] > b1v) { b1v = acc[e]; i1 = e; }
        float b2v = -1e30f; int i2 = 0;
#pragma unroll
        for (int e = 0; e < NEXP; e++) if (e != i1 && acc[e] > b2v) { b2v = acc[e]; i2 = e; }
        float e2 = __expf(b2v - b1v);
        float inv = 1.f / (1.f + e2);
        topi[t * 2] = i1; topi[t * 2 + 1] = i2;
        topw[t * 2] = inv; topw[t * 2 + 1] = e2 * inv;
        atomicAdd(&counts[i1], 1);
        atomicAdd(&counts[i2], 1);
    }
}

// ---------------- scan: 128-padded exclusive prefix ----------------
__global__ void scan_kernel(const int* __restrict__ counts,
                            int* __restrict__ offsets, int* __restrict__ cursor)
{
    if (threadIdx.x == 0 && blockIdx.x == 0) {
        int off = 0;
        for (int e = 0; e < NEXP; e++) {
            offsets[e] = off;
            cursor[e]  = off;
            off += (counts[e] + 127) & ~127;
        }
    }
}

// ---------------- gather: one wave per (token, k) slot ----------------
__global__ __launch_bounds__(64) void gather_kernel(
    const float* __restrict__ x, const int* __restrict__ topi,
    int* __restrict__ cursor, int* __restrict__ slot_of,
    unsigned short* __restrict__ Xe)
{
    int b = blockIdx.x;          // 0..N*TOPK-1
    int t = b >> 1;
    __shared__ int spos;
    if (threadIdx.x == 0) {
        int e = topi[b];
        int pos = atomicAdd(&cursor[e], 1);
        slot_of[b] = pos;
        spos = pos;
    }
    __syncthreads();
    int pos = spos;
    const float* src = x + (size_t)t * D_IN;
    unsigned short* dst = Xe + (size_t)pos * D_IN;
    int l = threadIdx.x;
#pragma unroll
    for (int i = 0; i < 4; i++) {
        float4 f = *(const float4*)(src + l * 4 + i * 256);
        uint2 p; p.x = pack2(f.x, f.y); p.y = pack2(f.z, f.w);
        *(uint2*)(dst + l * 4 + i * 256) = p;
    }
}

// ---------------- grouped GEMM (pure bf16, conflict-free LDS) --------------
// A: [rows, KDIM] bf16. Wb: [E, NDIM, KDIM] bf16. Tile 128x128, BK=64,
// 4 waves x (4x4) 16x16x32 MFMA, 2 k-steps per iter.
// LDS = sequence of 1KB issue-blocks: block (seg*2+t) holds rows seg*16..+15,
// k-half t, laid out [chunk(l>>4)][row(l&15)] so both global_load_lds dest and
// fragment ds_read_b128 are linear in lane (zero bank conflicts).
// OUT_MODE: 0 = fp32 store (+bias), 1 = bf16 store (+bias), 2 = fp32 store
// to split-K partial buffer (no bias), chunk kc = blockIdx.z % SPLITK.
template <int KDIM, int NDIM, int SPLITK, bool RELU, int OUT_MODE>
__global__ __launch_bounds__(256) void moe_gemm(
    const unsigned short* __restrict__ A, const unsigned short* __restrict__ Wb,
    const float* __restrict__ bias, void* __restrict__ Out,
    const int* __restrict__ counts, const int* __restrict__ offsets)
{
    constexpr int KCHUNK = KDIM / SPLITK;
    int e  = blockIdx.z / SPLITK;
    int kc = blockIdx.z % SPLITK;
    int cnt = counts[e];
    int tm = blockIdx.y;
    if (tm * 128 >= cnt) return;
    int m0 = offsets[e] + tm * 128;
    int n0 = blockIdx.x * 128;

    __shared__ __align__(16) unsigned short As[128 * 64];  // 16 KB
    __shared__ __align__(16) unsigned short Bs[128 * 64];  // 16 KB

    int tid = threadIdx.x;
    int wave = tid >> 6, lane = tid & 63;

    const unsigned short* We = Wb + (size_t)e * NDIM * KDIM;

    f32x4 acc[4][4];
#pragma unroll
    for (int i = 0; i < 4; i++)
#pragma unroll
        for (int j = 0; j < 4; j++) acc[i][j] = (f32x4){0.f, 0.f, 0.f, 0.f};

    int m_off = (wave & 1) * 64;
    int n_off = (wave >> 1) * 64;
    int aseg = (m_off >> 4);   // 0 or 4
    int bseg = (n_off >> 4);

    int r16 = lane & 15;       // staged row within a 16-row segment
    int kq8 = (lane >> 4) * 8; // staged k-offset (shorts) within a 32-k half

    for (int k0 = kc * KCHUNK; k0 < kc * KCHUNK + KCHUNK; k0 += 64) {
        // stage A & B: wave w handles segments w and w+4, both k-halves
#pragma unroll
        for (int si = 0; si < 2; si++) {
            int s = wave + si * 4;
#pragma unroll
            for (int t = 0; t < 2; t++) {
                const unsigned short* ga =
                    A + (size_t)(m0 + s * 16 + r16) * KDIM + k0 + t * 32 + kq8;
                async_copy16(ga, (char*)As + ((s * 2 + t) << 10));
                const unsigned short* gb2 =
                    We + (size_t)(n0 + s * 16 + r16) * KDIM + k0 + t * 32 + kq8;
                async_copy16(gb2, (char*)Bs + ((s * 2 + t) << 10));
            }
        }
        __syncthreads();   // drains vmcnt (global_load_lds) before reads

#pragma unroll
        for (int t = 0; t < 2; t++) {
            bf16x8 af[4], bfr[4];
#pragma unroll
            for (int mi = 0; mi < 4; mi++)
                af[mi] = *(const bf16x8*)&As[((aseg + mi) * 2 + t) * 512 + lane * 8];
#pragma unroll
            for (int ni = 0; ni < 4; ni++)
                bfr[ni] = *(const bf16x8*)&Bs[((bseg + ni) * 2 + t) * 512 + lane * 8];
#pragma unroll
            for (int mi = 0; mi < 4; mi++)
#pragma unroll
                for (int ni = 0; ni < 4; ni++)
                    acc[mi][ni] = __builtin_amdgcn_mfma_f32_16x16x32_bf16(
                        af[mi], bfr[ni], acc[mi][ni], 0, 0, 0);
        }
        __syncthreads();
    }

    // epilogue: C/D map col=lane&15, row=(lane>>4)*4+r
    float* outP = (float*)Out;
    if (OUT_MODE == 2) outP += (size_t)kc * ROW_CAP * NDIM;
#pragma unroll
    for (int ni = 0; ni < 4; ni++) {
        int col = n0 + n_off + ni * 16 + (lane & 15);
        float bv = (OUT_MODE == 2) ? 0.f : bias[(size_t)e * NDIM + col];
#pragma unroll
        for (int mi = 0; mi < 4; mi++) {
            int row = m0 + m_off + mi * 16 + ((lane >> 4) * 4);
#pragma unroll
            for (int r2 = 0; r2 < 4; r2++) {
                float v = acc[mi][ni][r2] + bv;
                if (RELU) v = fmaxf(v, 0.f);
                if (OUT_MODE == 1)
                    ((unsigned short*)Out)[(size_t)(row + r2) * NDIM + col] = f2bf(v);
                else
                    outP[(size_t)(row + r2) * NDIM + col] = v;
            }
        }
    }
}

// ------- combine: out[t] = sum_j w_j * (b2[e_j] + sum_kc Yp[kc][s_j]) ------
__global__ __launch_bounds__(256) void combine_kernel(
    const float* __restrict__ Yp, const int* __restrict__ slot_of,
    const int* __restrict__ topi, const float* __restrict__ topw,
    const float* __restrict__ b2, float* __restrict__ out)
{
    int t = blockIdx.x;
    int i = threadIdx.x;
    float4 o = {0.f, 0.f, 0.f, 0.f};
#pragma unroll
    for (int j = 0; j < TOPK; j++) {
        int s = slot_of[t * 2 + j];
        int e = topi[t * 2 + j];
        float w = topw[t * 2 + j];
        float4 acc = *(const float4*)(b2 + (size_t)e * D_OUT + i * 4);
#pragma unroll
        for (int kc = 0; kc < 4; kc++) {
            float4 y = *(const float4*)(Yp + ((size_t)kc * ROW_CAP + s) * D_OUT + i * 4);
            acc.x += y.x; acc.y += y.y; acc.z += y.z; acc.w += y.w;
        }
        o.x += w * acc.x; o.y += w * acc.y; o.z += w * acc.z; o.w += w * acc.w;
    }
    *(float4*)(out + (size_t)t * D_OUT + i * 4) = o;
}

extern "C" void kernel_launch(void* const* d_in, const int* in_sizes, int n_in,
                              void* d_out, int out_size, void* d_ws, size_t ws_size,
                              hipStream_t stream)
{
    const float* x  = (const float*)d_in[0];
    const float* gw = (const float*)d_in[1];
    const float* gb = (const float*)d_in[2];
    const float* W1 = (const float*)d_in[3];
    const float* b1 = (const float*)d_in[4];
    const float* W2 = (const float*)d_in[5];
    const float* b2 = (const float*)d_in[6];
    float* out = (float*)d_out;

    char* ws = (char*)d_ws;
    int* counts  = (int*)ws;                 // 8 ints
    int* cursor  = counts + 8;               // 8 ints
    int* offsets = counts + 16;              // 8 ints
    int* topi    = counts + 32;              // 4096 ints
    int* slot_of = counts + 32 + 4096;       // 4096 ints
    float* topw  = (float*)(counts + 32 + 8192);  // 4096 floats

    // Layout (MB): ctrl 0.07 | Xe 10.5 | H 41.9 | W2b 67.1 | W1b 67.1
    // Y (split-K fp32 partials, 83.9) OVERLAYS W1b (dead after GEMM1) + tail.
    const size_t XE_OFF  = 1ull << 16;
    const size_t H_OFF   = XE_OFF  + (size_t)ROW_CAP * D_IN  * 2;
    const size_t W2B_OFF = H_OFF   + (size_t)ROW_CAP * D_HID * 2;
    const size_t W1B_OFF = W2B_OFF + (size_t)NEXP * D_OUT * D_HID * 2;
    const size_t Y_OFF   = W1B_OFF;   // overlay: Y (4*ROW_CAP*D_OUT*4 = 84MB)
    unsigned short* Xe  = (unsigned short*)(ws + XE_OFF);
    unsigned short* H   = (unsigned short*)(ws + H_OFF);
    unsigned short* W2b = (unsigned short*)(ws + W2B_OFF);
    unsigned short* W1b = (unsigned short*)(ws + W1B_OFF);
    float*          Y   = (float*)(ws + Y_OFF);

    hipMemsetAsync(d_ws, 0, 128, stream);   // counts + cursor

    const int W1_N4 = NEXP * D_HID * D_IN / 4;
    const int W2_N4 = NEXP * D_OUT * D_HID / 4;
    convert_w<<<4096, 256, 0, stream>>>((const float4*)W1, (uint2*)W1b, W1_N4);
    convert_w<<<4096, 256, 0, stream>>>((const float4*)W2, (uint2*)W2b, W2_N4);

    gate_kernel<<<N_TOK / 4, 256, 0, stream>>>(x, gw, gb, topi, topw, counts);
    scan_kernel<<<1, 64, 0, stream>>>(counts, offsets, cursor);
    gather_kernel<<<N_TOK * TOPK, 64, 0, stream>>>(x, topi, cursor, slot_of, Xe);

    // GEMM1: H = relu(Xe @ W1^T + b1), bf16 out
    moe_gemm<D_IN, D_HID, 1, true, 1><<<dim3(D_HID / 128, 16, NEXP), 256, 0, stream>>>(
        Xe, W1b, b1, (void*)H, counts, offsets);
    // GEMM2: Yp[kc] = H @ W2^T chunk partials (split-K=4, plain fp32 stores)
    moe_gemm<D_HID, D_OUT, 4, false, 2><<<dim3(D_OUT / 128, 16, NEXP * 4), 256, 0, stream>>>(
        H, W2b, b2, (void*)Y, counts, offsets);

    combine_kernel<<<N_TOK, 256, 0, stream>>>(Y, slot_of, topi, topw, b2, out);
}